// Round 3
// baseline (344.235 us; speedup 1.0000x reference)
//
#include <hip/hip_runtime.h>
#include <hip/hip_bf16.h>
#include <math.h>

// AttentionBlock: GN(8 groups) -> 1x1 conv q,k,v -> softmax(q^T k / 16) v -> 1x1 proj + residual
// b=4, c=256, hw=4096. All-bf16 MFMA pipeline.
//
// R3: flash v3 — 32 q-rows/wave (two subtiles share K/V frags), V fragments
// direct from global (L2), K-only LDS staging, NCHUNK=4 with partial-O
// buffers placed in d_out scratch (Op1/Op2) so ws footprint stays ~42 MB.
// Wq/Wk/Wv pre-converted to bf16 once (qkv was VALU-conversion-bound).

#define CCH 256
#define NPIX 4096
#define NB 4
#define NG 8
#define EPS 1e-5f
#define NCHUNK 4

typedef __attribute__((ext_vector_type(8))) short short8;
typedef __attribute__((ext_vector_type(4))) short short4v;
typedef __attribute__((ext_vector_type(4))) float f32x4;
typedef unsigned short ushort_t;

__device__ inline ushort_t f2bf(float x) {
    union { float f; unsigned u; } c; c.f = x;
    unsigned r = c.u + 0x7FFFu + ((c.u >> 16) & 1u);
    return (ushort_t)(r >> 16);
}
__device__ inline float bf2f(ushort_t h) {
    union { unsigned u; float f; } c; c.u = ((unsigned)h) << 16;
    return c.f;
}

// ---------------- Weight f32 -> bf16 (once) ----------------
__global__ __launch_bounds__(256) void wconv(const float* __restrict__ w0,
                                             const float* __restrict__ w1,
                                             const float* __restrict__ w2,
                                             ushort_t* __restrict__ dst) {
    int wi = blockIdx.y;
    const float* src = wi == 0 ? w0 : wi == 1 ? w1 : w2;
    int i = (blockIdx.x * 256 + threadIdx.x) * 4;
    float4 v = *(const float4*)(src + i);
    short4v o;
    o[0] = (short)f2bf(v.x); o[1] = (short)f2bf(v.y);
    o[2] = (short)f2bf(v.z); o[3] = (short)f2bf(v.w);
    *(short4v*)(dst + (size_t)wi * CCH * CCH + i) = o;
}

// ---------------- GroupNorm stats: stage 1 ----------------
__global__ __launch_bounds__(256) void gn_stage1(const float* __restrict__ x, float* __restrict__ part) {
    int bid = blockIdx.x;
    int bg = bid >> 3;
    int slice = bid & 7;
    const float* base = x + (size_t)bg * 32 * NPIX + (size_t)slice * 16384;
    int t = threadIdx.x;
    float s = 0.f, sq = 0.f;
    for (int i = t; i < 4096; i += 256) {
        float4 v = ((const float4*)base)[i];
        s  += v.x + v.y + v.z + v.w;
        sq += v.x*v.x + v.y*v.y + v.z*v.z + v.w*v.w;
    }
    for (int off = 32; off; off >>= 1) {
        s  += __shfl_down(s,  off);
        sq += __shfl_down(sq, off);
    }
    __shared__ float red[8];
    int wid = t >> 6;
    if ((t & 63) == 0) { red[wid*2] = s; red[wid*2+1] = sq; }
    __syncthreads();
    if (t == 0) {
        float ts = 0.f, tq = 0.f;
        for (int wv = 0; wv < 4; wv++) { ts += red[wv*2]; tq += red[wv*2+1]; }
        part[bid*2] = ts; part[bid*2+1] = tq;
    }
}

// ---------------- GroupNorm stats: stage 2 ----------------
__global__ __launch_bounds__(64) void gn_stage2(const float* __restrict__ part, float* __restrict__ stats) {
    int t = threadIdx.x;
    if (t < 32) {
        float s = 0.f, sq = 0.f;
        for (int i = 0; i < 8; i++) { s += part[(t*8+i)*2]; sq += part[(t*8+i)*2+1]; }
        const float inv = 1.f / 131072.f;
        float mean = s * inv;
        float var = sq * inv - mean * mean;
        stats[t*2] = mean;
        stats[t*2+1] = rsqrtf(var + EPS);
    }
}

// ---------------- GN apply + transpose: x[b][c][n] f32 -> xnT[b][n][c] bf16 ----------------
__global__ __launch_bounds__(256) void gn_transpose(const float* __restrict__ x,
                                                    const float* __restrict__ stats,
                                                    const float* __restrict__ gamma,
                                                    const float* __restrict__ beta,
                                                    ushort_t* __restrict__ xnT) {
    __shared__ float T[64][68];
    int t = threadIdx.x;
    int nBase = blockIdx.x * 64;
    int cBase = blockIdx.y * 64;
    int b = blockIdx.z;
    const float* xb = x + (size_t)b * CCH * NPIX;

    int n4  = (t & 15) * 4;
    int cc0 = (t >> 4) * 4;
    for (int i = 0; i < 4; i++) {
        int cc = cc0 + i;
        int c = cBase + cc;
        int g = c >> 5;
        float mean = stats[(b*NG + g)*2];
        float rstd = stats[(b*NG + g)*2 + 1];
        float ga = gamma[c] * rstd;
        float be = beta[c] - mean * ga;
        float4 v = *(const float4*)&xb[(size_t)c * NPIX + nBase + n4];
        T[cc][n4+0] = v.x * ga + be;
        T[cc][n4+1] = v.y * ga + be;
        T[cc][n4+2] = v.z * ga + be;
        T[cc][n4+3] = v.w * ga + be;
    }
    __syncthreads();
    int nn  = t >> 2;
    int ci0 = (t & 3) * 16;
    short8 o0, o1;
    for (int j = 0; j < 8; j++) {
        o0[j] = (short)f2bf(T[ci0 + j][nn]);
        o1[j] = (short)f2bf(T[ci0 + 8 + j][nn]);
    }
    ushort_t* dst = xnT + ((size_t)b * NPIX + nBase + nn) * CCH + cBase + ci0;
    *(short8*)dst = o0;
    *((short8*)dst + 1) = o1;
}

// ---------------- QKV GEMM (bf16 weights): qT,kT[b][n][c], v[b][c][n] ----------------
__global__ __launch_bounds__(256) void qkv_gemm(const ushort_t* __restrict__ xnT,
                                                const ushort_t* __restrict__ wqb,
                                                const ushort_t* __restrict__ wkb,
                                                const ushort_t* __restrict__ wvb,
                                                const float* __restrict__ bq,
                                                const float* __restrict__ bk,
                                                const float* __restrict__ bv,
                                                ushort_t* __restrict__ qT, ushort_t* __restrict__ kT,
                                                ushort_t* __restrict__ vv) {
    __shared__ __align__(16) ushort_t Xs[64*40];
    __shared__ __align__(16) ushort_t Wqs[64*40];
    __shared__ __align__(16) ushort_t Wks[64*40];
    __shared__ __align__(16) ushort_t Wvs[64*40];
    int t = threadIdx.x;
    int w = t >> 6, l = t & 63, quad = l >> 4, l16 = l & 15;
    int nBase = blockIdx.x * 64, oBase = blockIdx.y * 64, b = blockIdx.z;

    const f32x4 fz = {0.f, 0.f, 0.f, 0.f};
    f32x4 accQ[4], accK[4], accV[4];
    for (int i = 0; i < 4; i++) { accQ[i] = fz; accK[i] = fz; accV[i] = fz; }

    int srow = t >> 2, sseg = t & 3;
    const ushort_t* xsrc  = xnT + ((size_t)b * NPIX + nBase + srow) * CCH + sseg * 8;
    const ushort_t* wqsrc = wqb + (size_t)(oBase + srow) * CCH + sseg * 8;
    const ushort_t* wksrc = wkb + (size_t)(oBase + srow) * CCH + sseg * 8;
    const ushort_t* wvsrc = wvb + (size_t)(oBase + srow) * CCH + sseg * 8;
    int sdst = srow * 40 + sseg * 8;

    for (int cb = 0; cb < 8; cb++) {
        __syncthreads();
        *(short8*)&Xs [sdst] = *(const short8*)(xsrc  + cb * 32);
        *(short8*)&Wqs[sdst] = *(const short8*)(wqsrc + cb * 32);
        *(short8*)&Wks[sdst] = *(const short8*)(wksrc + cb * 32);
        *(short8*)&Wvs[sdst] = *(const short8*)(wvsrc + cb * 32);
        __syncthreads();
        short8 xa  = *(short8*)&Xs [(16*w + l16)*40 + quad*8];
        short8 wva = *(short8*)&Wvs[(16*w + l16)*40 + quad*8];
        #pragma unroll
        for (int ob = 0; ob < 4; ob++) {
            short8 wqb2 = *(short8*)&Wqs[(16*ob + l16)*40 + quad*8];
            short8 wkb2 = *(short8*)&Wks[(16*ob + l16)*40 + quad*8];
            short8 xb   = *(short8*)&Xs [(16*ob + l16)*40 + quad*8];
            accQ[ob] = __builtin_amdgcn_mfma_f32_16x16x32_bf16(xa,  wqb2, accQ[ob], 0, 0, 0);
            accK[ob] = __builtin_amdgcn_mfma_f32_16x16x32_bf16(xa,  wkb2, accK[ob], 0, 0, 0);
            accV[ob] = __builtin_amdgcn_mfma_f32_16x16x32_bf16(wva, xb,   accV[ob], 0, 0, 0);
        }
    }
    #pragma unroll
    for (int ob = 0; ob < 4; ob++) {
        int ocol = oBase + 16*ob + l16;
        float bqv = bq[ocol], bkv = bk[ocol];
        #pragma unroll
        for (int r = 0; r < 4; r++) {
            int nrow = nBase + 16*w + quad*4 + r;
            size_t idx = ((size_t)b * NPIX + nrow) * CCH + ocol;
            qT[idx] = f2bf(accQ[ob][r] + bqv);
            kT[idx] = f2bf(accK[ob][r] + bkv);
        }
        int ncol = nBase + 16*ob + l16;
        #pragma unroll
        for (int r = 0; r < 4; r++) {
            int orow = oBase + 16*w + quad*4 + r;
            vv[((size_t)b * CCH + orow) * NPIX + ncol] = f2bf(accV[ob][r] + bv[orow]);
        }
    }
}

// ---------------- Flash attention v3 ----------------
// Grid (32 qtiles(128q), NCHUNK, 4 b), block 256 = 4 waves; wave w: q rows
// [qBase+32w, +32) as two 16-row subtiles sharing K/V fragments. K staged in
// LDS with even/odd permutation (packed u32 P writes); V frags direct from
// global. Writes unnormalized partial O (bf16) + partial row-sums l (f32).
__global__ __launch_bounds__(256, 2) void flash_attn(const ushort_t* __restrict__ qT,
                                                     const ushort_t* __restrict__ kT,
                                                     const ushort_t* __restrict__ vv,
                                                     ushort_t* __restrict__ Op0,
                                                     ushort_t* __restrict__ Op1,
                                                     ushort_t* __restrict__ Op2,
                                                     ushort_t* __restrict__ Op3,
                                                     float* __restrict__ lsum) {
    __shared__ __align__(16) ushort_t Ks[32*264];   // 16.9 KB
    __shared__ __align__(16) ushort_t Ps[4*32*40];  // 10.2 KB
    int t = threadIdx.x;
    int w = t >> 6, l = t & 63, quad = l >> 4, l16 = l & 15;
    int qBase = blockIdx.x * 128, chunk = blockIdx.y, b = blockIdx.z;
    int qw = qBase + w * 32;

    // Q fragments for both subtiles (A-layout: [m=l16][k=quad*8+j])
    short8 qf[2][8];
    #pragma unroll
    for (int s = 0; s < 2; s++) {
        const ushort_t* qrow = qT + ((size_t)b * NPIX + qw + s*16 + l16) * CCH + quad * 8;
        #pragma unroll
        for (int cb = 0; cb < 8; cb++) qf[s][cb] = *(const short8*)(qrow + cb * 32);
    }

    const f32x4 fz = {0.f, 0.f, 0.f, 0.f};
    f32x4 accO[2][16];
    #pragma unroll
    for (int s = 0; s < 2; s++)
        #pragma unroll
        for (int i = 0; i < 16; i++) accO[s][i] = fz;
    float lrow[2][4] = {{0.f,0.f,0.f,0.f},{0.f,0.f,0.f,0.f}};

    // K staging: physical row p holds kv 2*(p&15)+(p>>4) -> s0 even cols, s1 odd
    int krow = t >> 3, kseg = t & 7;
    int kvm = 2 * (krow & 15) + (krow >> 4);
    const ushort_t* ksrc0 = kT + ((size_t)b * NPIX + kvm) * CCH + kseg * 32;
    ushort_t* kdst = &Ks[krow * 264 + kseg * 32];
    // V direct-global: lane reads c = cb*16 + l16, m = mBase + quad*8 .. +7
    const ushort_t* vbase = vv + ((size_t)b * CCH + l16) * NPIX + quad * 8;
    ushort_t* Pw = &Ps[w * 32 * 40];

    const float SC = 0.0625f * 1.44269504089f;   // (1/16) * log2(e)
    int mStart = chunk * (NPIX / NCHUNK);
    for (int mBase = mStart; mBase < mStart + NPIX / NCHUNK; mBase += 32) {
        __syncthreads();
        const ushort_t* ks = ksrc0 + (size_t)mBase * CCH;
        #pragma unroll
        for (int i = 0; i < 4; i++) *(short8*)(kdst + i*8) = *(const short8*)(ks + i*8);
        __syncthreads();

        f32x4 s00 = fz, s01 = fz, s10 = fz, s11 = fz;
        #pragma unroll
        for (int cb = 0; cb < 8; cb++) {
            short8 k0 = *(short8*)&Ks[(l16     ) * 264 + cb*32 + quad*8];
            short8 k1 = *(short8*)&Ks[(16 + l16) * 264 + cb*32 + quad*8];
            s00 = __builtin_amdgcn_mfma_f32_16x16x32_bf16(qf[0][cb], k0, s00, 0, 0, 0);
            s01 = __builtin_amdgcn_mfma_f32_16x16x32_bf16(qf[0][cb], k1, s01, 0, 0, 0);
            s10 = __builtin_amdgcn_mfma_f32_16x16x32_bf16(qf[1][cb], k0, s10, 0, 0, 0);
            s11 = __builtin_amdgcn_mfma_f32_16x16x32_bf16(qf[1][cb], k1, s11, 0, 0, 0);
        }
        // max-free softmax numerators; s*0 -> kv col 2*l16, s*1 -> 2*l16+1
        #pragma unroll
        for (int r = 0; r < 4; r++) {
            float p0 = exp2f(s00[r] * SC);
            float p1 = exp2f(s01[r] * SC);
            lrow[0][r] += p0 + p1;
            ((unsigned*)Pw)[(quad*4 + r) * 20 + l16] =
                ((unsigned)f2bf(p1) << 16) | (unsigned)f2bf(p0);
            float p2 = exp2f(s10[r] * SC);
            float p3 = exp2f(s11[r] * SC);
            lrow[1][r] += p2 + p3;
            ((unsigned*)Pw)[(16 + quad*4 + r) * 20 + l16] =
                ((unsigned)f2bf(p3) << 16) | (unsigned)f2bf(p2);
        }
        short8 pf0 = *(short8*)&Pw[(l16     ) * 40 + quad*8];  // wave-private
        short8 pf1 = *(short8*)&Pw[(16 + l16) * 40 + quad*8];
        const ushort_t* vp = vbase + mBase;
        #pragma unroll
        for (int cb = 0; cb < 16; cb++) {
            short8 vf = *(const short8*)(vp + (size_t)cb * 16 * NPIX);
            accO[0][cb] = __builtin_amdgcn_mfma_f32_16x16x32_bf16(pf0, vf, accO[0][cb], 0, 0, 0);
            accO[1][cb] = __builtin_amdgcn_mfma_f32_16x16x32_bf16(pf1, vf, accO[1][cb], 0, 0, 0);
        }
    }

    // partial row-sums: reduce over the 16 l16 lanes
    #pragma unroll
    for (int s = 0; s < 2; s++)
        #pragma unroll
        for (int r = 0; r < 4; r++) {
            float v = lrow[s][r];
            v += __shfl_xor(v, 1);
            v += __shfl_xor(v, 2);
            v += __shfl_xor(v, 4);
            v += __shfl_xor(v, 8);
            if (l16 == 0)
                lsum[((size_t)chunk * NB + b) * NPIX + qw + s*16 + quad*4 + r] = v;
        }
    // unnormalized partial O in bf16
    ushort_t* op = chunk == 0 ? Op0 : chunk == 1 ? Op1 : chunk == 2 ? Op2 : Op3;
    #pragma unroll
    for (int s = 0; s < 2; s++)
        #pragma unroll
        for (int cb = 0; cb < 16; cb++)
            #pragma unroll
            for (int r = 0; r < 4; r++) {
                int nrow = qw + s*16 + quad*4 + r;
                op[((size_t)b * NPIX + nrow) * CCH + cb*16 + l16] = f2bf(accO[s][cb][r]);
            }
}

// ---------------- Combine: aoT = (Op0+Op1+Op2+Op3)/(l0+l1+l2+l3), in-place Op0 ----------------
__global__ __launch_bounds__(256) void attn_combine(ushort_t* __restrict__ Op0,
                                                    const ushort_t* __restrict__ Op1,
                                                    const ushort_t* __restrict__ Op2,
                                                    const ushort_t* __restrict__ Op3,
                                                    const float* __restrict__ lsum) {
    const size_t BN = (size_t)NB * NPIX;
    size_t base = ((size_t)blockIdx.x * 256 + threadIdx.x) * 4;
    size_t bn = base >> 8;
    float li = 1.f / (lsum[bn] + lsum[BN + bn] + lsum[2*BN + bn] + lsum[3*BN + bn]);
    short4v a0 = *(short4v*)&Op0[base];
    short4v a1 = *(const short4v*)&Op1[base];
    short4v a2 = *(const short4v*)&Op2[base];
    short4v a3 = *(const short4v*)&Op3[base];
    short4v o;
    #pragma unroll
    for (int i = 0; i < 4; i++) {
        float v = (bf2f((ushort_t)a0[i]) + bf2f((ushort_t)a1[i]) +
                   bf2f((ushort_t)a2[i]) + bf2f((ushort_t)a3[i])) * li;
        o[i] = (short)f2bf(v);
    }
    *(short4v*)&Op0[base] = o;
}

// ---------------- Projection GEMM + bias + residual: out[b][c][n] f32 ----------------
__global__ __launch_bounds__(256) void proj_gemm(const ushort_t* __restrict__ aoT,
                                                 const float* __restrict__ wp, const float* __restrict__ bp,
                                                 const float* __restrict__ x, float* __restrict__ out) {
    __shared__ __align__(16) ushort_t As[64*40];
    __shared__ __align__(16) ushort_t Bs[64*40];
    int t = threadIdx.x;
    int w = t >> 6, l = t & 63, quad = l >> 4, l16 = l & 15;
    int nBase = blockIdx.x * 64, oBase = blockIdx.y * 64, b = blockIdx.z;

    const f32x4 fz = {0.f, 0.f, 0.f, 0.f};
    f32x4 acc[4];
    for (int i = 0; i < 4; i++) acc[i] = fz;

    int srow = t >> 2, sseg = t & 3;
    const float* wsrc = wp + (size_t)(oBase + srow) * CCH + sseg * 8;
    const ushort_t* bsrc = aoT + ((size_t)b * NPIX + nBase + srow) * CCH + sseg * 8;
    int sdst = srow * 40 + sseg * 8;

    for (int cb = 0; cb < 8; cb++) {
        __syncthreads();
        {
            float4 a = *(const float4*)(wsrc + cb*32);
            float4 b4 = *(const float4*)(wsrc + cb*32 + 4);
            short8 h;
            h[0]=(short)f2bf(a.x); h[1]=(short)f2bf(a.y); h[2]=(short)f2bf(a.z); h[3]=(short)f2bf(a.w);
            h[4]=(short)f2bf(b4.x); h[5]=(short)f2bf(b4.y); h[6]=(short)f2bf(b4.z); h[7]=(short)f2bf(b4.w);
            *(short8*)&As[sdst] = h;
        }
        *(short8*)&Bs[sdst] = *(const short8*)(bsrc + cb * 32);
        __syncthreads();
        short8 af = *(short8*)&As[(16*w + l16)*40 + quad*8];
        #pragma unroll
        for (int nb = 0; nb < 4; nb++) {
            short8 bf = *(short8*)&Bs[(16*nb + l16)*40 + quad*8];
            acc[nb] = __builtin_amdgcn_mfma_f32_16x16x32_bf16(af, bf, acc[nb], 0, 0, 0);
        }
    }
    #pragma unroll
    for (int nb = 0; nb < 4; nb++) {
        #pragma unroll
        for (int r = 0; r < 4; r++) {
            int orow = oBase + 16*w + quad*4 + r;
            int ncol = nBase + 16*nb + l16;
            size_t idx = ((size_t)b * CCH + orow) * NPIX + ncol;
            out[idx] = acc[nb][r] + bp[orow] + x[idx];
        }
    }
}

extern "C" void kernel_launch(void* const* d_in, const int* in_sizes, int n_in,
                              void* d_out, int out_size, void* d_ws, size_t ws_size,
                              hipStream_t stream) {
    const float* x     = (const float*)d_in[0];
    const float* gamma = (const float*)d_in[1];
    const float* beta  = (const float*)d_in[2];
    const float* wq    = (const float*)d_in[3];
    const float* bq    = (const float*)d_in[4];
    const float* wk    = (const float*)d_in[5];
    const float* bk    = (const float*)d_in[6];
    const float* wv    = (const float*)d_in[7];
    const float* bv    = (const float*)d_in[8];
    const float* wp    = (const float*)d_in[9];
    const float* bp    = (const float*)d_in[10];
    float* out = (float*)d_out;

    const size_t SZ = (size_t)NB * NPIX * CCH;     // 4.19M elems, 8 MB bf16
    // ws: part[512] stats[64] lsum[4*4*4096] then 5 bf16 slots (~42.2 MB)
    float* part  = (float*)d_ws;
    float* stats = part + 512;
    float* lsum  = stats + 64;
    ushort_t* slot0 = (ushort_t*)(lsum + (size_t)NCHUNK * NB * NPIX);
    ushort_t* Op3 = slot0;                // also spare slot
    ushort_t* qT  = slot0 + SZ;
    ushort_t* kT  = slot0 + 2*SZ;
    ushort_t* vv  = slot0 + 3*SZ;
    ushort_t* aoT = slot0 + 4*SZ;         // Op0, combined in-place -> aoT
    // d_out (16 MB) as scratch until proj_gemm:
    ushort_t* xnT = (ushort_t*)d_out;     // [0,8M): xnT, later Op1
    ushort_t* Op1 = (ushort_t*)d_out;
    ushort_t* Op2 = (ushort_t*)d_out + SZ;  // [8M,16M): wbf (pre-qkv), later Op2
    ushort_t* wbf = (ushort_t*)d_out + SZ;  // Wq,Wk,Wv bf16 (3*64K elems)

    wconv<<<dim3(64, 3), 256, 0, stream>>>(wq, wk, wv, wbf);
    gn_stage1<<<256, 256, 0, stream>>>(x, part);
    gn_stage2<<<1, 64, 0, stream>>>(part, stats);
    gn_transpose<<<dim3(64, 4, 4), 256, 0, stream>>>(x, stats, gamma, beta, xnT);
    qkv_gemm<<<dim3(64, 4, 4), 256, 0, stream>>>(xnT, wbf, wbf + CCH*CCH, wbf + 2*CCH*CCH,
                                                 bq, bk, bv, qT, kT, vv);
    flash_attn<<<dim3(32, NCHUNK, 4), 256, 0, stream>>>(qT, kT, vv, aoT, Op1, Op2, Op3, lsum);
    attn_combine<<<(int)(SZ / 1024), 256, 0, stream>>>(aoT, Op1, Op2, Op3, lsum);
    proj_gemm<<<dim3(64, 4, 4), 256, 0, stream>>>(aoT, wp, bp, x, out);
}

// Round 4
// 249.229 us; speedup vs baseline: 1.3812x; 1.3812x over previous
//
#include <hip/hip_runtime.h>
#include <hip/hip_bf16.h>
#include <math.h>

// AttentionBlock: GN(8 groups) -> 1x1 conv q,k,v -> softmax(q^T k / 16) v -> 1x1 proj + residual
// b=4, c=256, hw=4096. All-bf16 MFMA pipeline.
//
// R4: flash v4 = R3's 32q/wave dual-subtile (shares K/V frags across 2
// subtiles) + V restored to LDS staging (R3's direct-global V frags were
// 16x64B scattered segments -> vmem-latency-bound; that was the regression).

#define CCH 256
#define NPIX 4096
#define NB 4
#define NG 8
#define EPS 1e-5f
#define NCHUNK 4

typedef __attribute__((ext_vector_type(8))) short short8;
typedef __attribute__((ext_vector_type(4))) short short4v;
typedef __attribute__((ext_vector_type(4))) float f32x4;
typedef unsigned short ushort_t;

__device__ inline ushort_t f2bf(float x) {
    union { float f; unsigned u; } c; c.f = x;
    unsigned r = c.u + 0x7FFFu + ((c.u >> 16) & 1u);
    return (ushort_t)(r >> 16);
}
__device__ inline float bf2f(ushort_t h) {
    union { unsigned u; float f; } c; c.u = ((unsigned)h) << 16;
    return c.f;
}

// ---------------- Weight f32 -> bf16 (once) ----------------
__global__ __launch_bounds__(256) void wconv(const float* __restrict__ w0,
                                             const float* __restrict__ w1,
                                             const float* __restrict__ w2,
                                             ushort_t* __restrict__ dst) {
    int wi = blockIdx.y;
    const float* src = wi == 0 ? w0 : wi == 1 ? w1 : w2;
    int i = (blockIdx.x * 256 + threadIdx.x) * 4;
    float4 v = *(const float4*)(src + i);
    short4v o;
    o[0] = (short)f2bf(v.x); o[1] = (short)f2bf(v.y);
    o[2] = (short)f2bf(v.z); o[3] = (short)f2bf(v.w);
    *(short4v*)(dst + (size_t)wi * CCH * CCH + i) = o;
}

// ---------------- GroupNorm stats: stage 1 ----------------
__global__ __launch_bounds__(256) void gn_stage1(const float* __restrict__ x, float* __restrict__ part) {
    int bid = blockIdx.x;
    int bg = bid >> 3;
    int slice = bid & 7;
    const float* base = x + (size_t)bg * 32 * NPIX + (size_t)slice * 16384;
    int t = threadIdx.x;
    float s = 0.f, sq = 0.f;
    for (int i = t; i < 4096; i += 256) {
        float4 v = ((const float4*)base)[i];
        s  += v.x + v.y + v.z + v.w;
        sq += v.x*v.x + v.y*v.y + v.z*v.z + v.w*v.w;
    }
    for (int off = 32; off; off >>= 1) {
        s  += __shfl_down(s,  off);
        sq += __shfl_down(sq, off);
    }
    __shared__ float red[8];
    int wid = t >> 6;
    if ((t & 63) == 0) { red[wid*2] = s; red[wid*2+1] = sq; }
    __syncthreads();
    if (t == 0) {
        float ts = 0.f, tq = 0.f;
        for (int wv = 0; wv < 4; wv++) { ts += red[wv*2]; tq += red[wv*2+1]; }
        part[bid*2] = ts; part[bid*2+1] = tq;
    }
}

// ---------------- GroupNorm stats: stage 2 ----------------
__global__ __launch_bounds__(64) void gn_stage2(const float* __restrict__ part, float* __restrict__ stats) {
    int t = threadIdx.x;
    if (t < 32) {
        float s = 0.f, sq = 0.f;
        for (int i = 0; i < 8; i++) { s += part[(t*8+i)*2]; sq += part[(t*8+i)*2+1]; }
        const float inv = 1.f / 131072.f;
        float mean = s * inv;
        float var = sq * inv - mean * mean;
        stats[t*2] = mean;
        stats[t*2+1] = rsqrtf(var + EPS);
    }
}

// ---------------- GN apply + transpose: x[b][c][n] f32 -> xnT[b][n][c] bf16 ----------------
__global__ __launch_bounds__(256) void gn_transpose(const float* __restrict__ x,
                                                    const float* __restrict__ stats,
                                                    const float* __restrict__ gamma,
                                                    const float* __restrict__ beta,
                                                    ushort_t* __restrict__ xnT) {
    __shared__ float T[64][68];
    int t = threadIdx.x;
    int nBase = blockIdx.x * 64;
    int cBase = blockIdx.y * 64;
    int b = blockIdx.z;
    const float* xb = x + (size_t)b * CCH * NPIX;

    int n4  = (t & 15) * 4;
    int cc0 = (t >> 4) * 4;
    for (int i = 0; i < 4; i++) {
        int cc = cc0 + i;
        int c = cBase + cc;
        int g = c >> 5;
        float mean = stats[(b*NG + g)*2];
        float rstd = stats[(b*NG + g)*2 + 1];
        float ga = gamma[c] * rstd;
        float be = beta[c] - mean * ga;
        float4 v = *(const float4*)&xb[(size_t)c * NPIX + nBase + n4];
        T[cc][n4+0] = v.x * ga + be;
        T[cc][n4+1] = v.y * ga + be;
        T[cc][n4+2] = v.z * ga + be;
        T[cc][n4+3] = v.w * ga + be;
    }
    __syncthreads();
    int nn  = t >> 2;
    int ci0 = (t & 3) * 16;
    short8 o0, o1;
    for (int j = 0; j < 8; j++) {
        o0[j] = (short)f2bf(T[ci0 + j][nn]);
        o1[j] = (short)f2bf(T[ci0 + 8 + j][nn]);
    }
    ushort_t* dst = xnT + ((size_t)b * NPIX + nBase + nn) * CCH + cBase + ci0;
    *(short8*)dst = o0;
    *((short8*)dst + 1) = o1;
}

// ---------------- QKV GEMM (bf16 weights): qT,kT[b][n][c], v[b][c][n] ----------------
__global__ __launch_bounds__(256) void qkv_gemm(const ushort_t* __restrict__ xnT,
                                                const ushort_t* __restrict__ wqb,
                                                const ushort_t* __restrict__ wkb,
                                                const ushort_t* __restrict__ wvb,
                                                const float* __restrict__ bq,
                                                const float* __restrict__ bk,
                                                const float* __restrict__ bv,
                                                ushort_t* __restrict__ qT, ushort_t* __restrict__ kT,
                                                ushort_t* __restrict__ vv) {
    __shared__ __align__(16) ushort_t Xs[64*40];
    __shared__ __align__(16) ushort_t Wqs[64*40];
    __shared__ __align__(16) ushort_t Wks[64*40];
    __shared__ __align__(16) ushort_t Wvs[64*40];
    int t = threadIdx.x;
    int w = t >> 6, l = t & 63, quad = l >> 4, l16 = l & 15;
    int nBase = blockIdx.x * 64, oBase = blockIdx.y * 64, b = blockIdx.z;

    const f32x4 fz = {0.f, 0.f, 0.f, 0.f};
    f32x4 accQ[4], accK[4], accV[4];
    for (int i = 0; i < 4; i++) { accQ[i] = fz; accK[i] = fz; accV[i] = fz; }

    int srow = t >> 2, sseg = t & 3;
    const ushort_t* xsrc  = xnT + ((size_t)b * NPIX + nBase + srow) * CCH + sseg * 8;
    const ushort_t* wqsrc = wqb + (size_t)(oBase + srow) * CCH + sseg * 8;
    const ushort_t* wksrc = wkb + (size_t)(oBase + srow) * CCH + sseg * 8;
    const ushort_t* wvsrc = wvb + (size_t)(oBase + srow) * CCH + sseg * 8;
    int sdst = srow * 40 + sseg * 8;

    for (int cb = 0; cb < 8; cb++) {
        __syncthreads();
        *(short8*)&Xs [sdst] = *(const short8*)(xsrc  + cb * 32);
        *(short8*)&Wqs[sdst] = *(const short8*)(wqsrc + cb * 32);
        *(short8*)&Wks[sdst] = *(const short8*)(wksrc + cb * 32);
        *(short8*)&Wvs[sdst] = *(const short8*)(wvsrc + cb * 32);
        __syncthreads();
        short8 xa  = *(short8*)&Xs [(16*w + l16)*40 + quad*8];
        short8 wva = *(short8*)&Wvs[(16*w + l16)*40 + quad*8];
        #pragma unroll
        for (int ob = 0; ob < 4; ob++) {
            short8 wqb2 = *(short8*)&Wqs[(16*ob + l16)*40 + quad*8];
            short8 wkb2 = *(short8*)&Wks[(16*ob + l16)*40 + quad*8];
            short8 xb   = *(short8*)&Xs [(16*ob + l16)*40 + quad*8];
            accQ[ob] = __builtin_amdgcn_mfma_f32_16x16x32_bf16(xa,  wqb2, accQ[ob], 0, 0, 0);
            accK[ob] = __builtin_amdgcn_mfma_f32_16x16x32_bf16(xa,  wkb2, accK[ob], 0, 0, 0);
            accV[ob] = __builtin_amdgcn_mfma_f32_16x16x32_bf16(wva, xb,   accV[ob], 0, 0, 0);
        }
    }
    #pragma unroll
    for (int ob = 0; ob < 4; ob++) {
        int ocol = oBase + 16*ob + l16;
        float bqv = bq[ocol], bkv = bk[ocol];
        #pragma unroll
        for (int r = 0; r < 4; r++) {
            int nrow = nBase + 16*w + quad*4 + r;
            size_t idx = ((size_t)b * NPIX + nrow) * CCH + ocol;
            qT[idx] = f2bf(accQ[ob][r] + bqv);
            kT[idx] = f2bf(accK[ob][r] + bkv);
        }
        int ncol = nBase + 16*ob + l16;
        #pragma unroll
        for (int r = 0; r < 4; r++) {
            int orow = oBase + 16*w + quad*4 + r;
            vv[((size_t)b * CCH + orow) * NPIX + ncol] = f2bf(accV[ob][r] + bv[orow]);
        }
    }
}

// ---------------- Flash attention v4 ----------------
// Grid (32 qtiles(128q), NCHUNK, 4 b), block 256 = 4 waves; wave w: q rows
// [qBase+32w, +32) as two 16-row subtiles sharing K/V fragments. K staged in
// LDS with even/odd permutation (packed u32 P writes); V staged in LDS.
// Writes unnormalized partial O (bf16) + partial row-sums l (f32).
__global__ __launch_bounds__(256, 2) void flash_attn(const ushort_t* __restrict__ qT,
                                                     const ushort_t* __restrict__ kT,
                                                     const ushort_t* __restrict__ vv,
                                                     ushort_t* __restrict__ Op0,
                                                     ushort_t* __restrict__ Op1,
                                                     ushort_t* __restrict__ Op2,
                                                     ushort_t* __restrict__ Op3,
                                                     float* __restrict__ lsum) {
    __shared__ __align__(16) ushort_t Ks[32*264];   // 16.9 KB
    __shared__ __align__(16) ushort_t Vs[256*40];   // 20.5 KB
    __shared__ __align__(16) ushort_t Ps[4*32*40];  // 10.2 KB
    int t = threadIdx.x;
    int w = t >> 6, l = t & 63, quad = l >> 4, l16 = l & 15;
    int qBase = blockIdx.x * 128, chunk = blockIdx.y, b = blockIdx.z;
    int qw = qBase + w * 32;

    // Q fragments for both subtiles (A-layout: [m=l16][k=quad*8+j])
    short8 qf[2][8];
    #pragma unroll
    for (int s = 0; s < 2; s++) {
        const ushort_t* qrow = qT + ((size_t)b * NPIX + qw + s*16 + l16) * CCH + quad * 8;
        #pragma unroll
        for (int cb = 0; cb < 8; cb++) qf[s][cb] = *(const short8*)(qrow + cb * 32);
    }

    const f32x4 fz = {0.f, 0.f, 0.f, 0.f};
    f32x4 accO[2][16];
    #pragma unroll
    for (int s = 0; s < 2; s++)
        #pragma unroll
        for (int i = 0; i < 16; i++) accO[s][i] = fz;
    float lrow[2][4] = {{0.f,0.f,0.f,0.f},{0.f,0.f,0.f,0.f}};

    // K staging: physical row p holds kv 2*(p&15)+(p>>4) -> s0 even cols, s1 odd
    int krow = t >> 3, kseg = t & 7;
    int kvm = 2 * (krow & 15) + (krow >> 4);
    const ushort_t* ksrc0 = kT + ((size_t)b * NPIX + kvm) * CCH + kseg * 32;
    ushort_t* kdst = &Ks[krow * 264 + kseg * 32];
    // V staging: thread t stages row c=t, 32 m-elems (64B)
    const ushort_t* vsrc0 = vv + ((size_t)b * CCH + t) * NPIX;
    ushort_t* vdst = &Vs[t * 40];
    ushort_t* Pw = &Ps[w * 32 * 40];

    const float SC = 0.0625f * 1.44269504089f;   // (1/16) * log2(e)
    int mStart = chunk * (NPIX / NCHUNK);
    for (int mBase = mStart; mBase < mStart + NPIX / NCHUNK; mBase += 32) {
        __syncthreads();
        const ushort_t* ks = ksrc0 + (size_t)mBase * CCH;
        #pragma unroll
        for (int i = 0; i < 4; i++) *(short8*)(kdst + i*8) = *(const short8*)(ks + i*8);
        const ushort_t* vsp = vsrc0 + mBase;
        #pragma unroll
        for (int i = 0; i < 4; i++) *(short8*)(vdst + i*8) = *(const short8*)(vsp + i*8);
        __syncthreads();

        f32x4 s00 = fz, s01 = fz, s10 = fz, s11 = fz;
        #pragma unroll
        for (int cb = 0; cb < 8; cb++) {
            short8 k0 = *(short8*)&Ks[(l16     ) * 264 + cb*32 + quad*8];
            short8 k1 = *(short8*)&Ks[(16 + l16) * 264 + cb*32 + quad*8];
            s00 = __builtin_amdgcn_mfma_f32_16x16x32_bf16(qf[0][cb], k0, s00, 0, 0, 0);
            s01 = __builtin_amdgcn_mfma_f32_16x16x32_bf16(qf[0][cb], k1, s01, 0, 0, 0);
            s10 = __builtin_amdgcn_mfma_f32_16x16x32_bf16(qf[1][cb], k0, s10, 0, 0, 0);
            s11 = __builtin_amdgcn_mfma_f32_16x16x32_bf16(qf[1][cb], k1, s11, 0, 0, 0);
        }
        // max-free softmax numerators; s*0 -> kv col 2*l16, s*1 -> 2*l16+1
        #pragma unroll
        for (int r = 0; r < 4; r++) {
            float p0 = exp2f(s00[r] * SC);
            float p1 = exp2f(s01[r] * SC);
            lrow[0][r] += p0 + p1;
            ((unsigned*)Pw)[(quad*4 + r) * 20 + l16] =
                ((unsigned)f2bf(p1) << 16) | (unsigned)f2bf(p0);
            float p2 = exp2f(s10[r] * SC);
            float p3 = exp2f(s11[r] * SC);
            lrow[1][r] += p2 + p3;
            ((unsigned*)Pw)[(16 + quad*4 + r) * 20 + l16] =
                ((unsigned)f2bf(p3) << 16) | (unsigned)f2bf(p2);
        }
        short8 pf0 = *(short8*)&Pw[(l16     ) * 40 + quad*8];  // wave-private
        short8 pf1 = *(short8*)&Pw[(16 + l16) * 40 + quad*8];
        #pragma unroll
        for (int cb = 0; cb < 16; cb++) {
            short8 vf = *(short8*)&Vs[(cb*16 + l16)*40 + quad*8];
            accO[0][cb] = __builtin_amdgcn_mfma_f32_16x16x32_bf16(pf0, vf, accO[0][cb], 0, 0, 0);
            accO[1][cb] = __builtin_amdgcn_mfma_f32_16x16x32_bf16(pf1, vf, accO[1][cb], 0, 0, 0);
        }
    }

    // partial row-sums: reduce over the 16 l16 lanes
    #pragma unroll
    for (int s = 0; s < 2; s++)
        #pragma unroll
        for (int r = 0; r < 4; r++) {
            float v = lrow[s][r];
            v += __shfl_xor(v, 1);
            v += __shfl_xor(v, 2);
            v += __shfl_xor(v, 4);
            v += __shfl_xor(v, 8);
            if (l16 == 0)
                lsum[((size_t)chunk * NB + b) * NPIX + qw + s*16 + quad*4 + r] = v;
        }
    // unnormalized partial O in bf16
    ushort_t* op = chunk == 0 ? Op0 : chunk == 1 ? Op1 : chunk == 2 ? Op2 : Op3;
    #pragma unroll
    for (int s = 0; s < 2; s++)
        #pragma unroll
        for (int cb = 0; cb < 16; cb++)
            #pragma unroll
            for (int r = 0; r < 4; r++) {
                int nrow = qw + s*16 + quad*4 + r;
                op[((size_t)b * NPIX + nrow) * CCH + cb*16 + l16] = f2bf(accO[s][cb][r]);
            }
}

// ---------------- Combine: aoT = (Op0+Op1+Op2+Op3)/(l0+l1+l2+l3), in-place Op0 ----------------
__global__ __launch_bounds__(256) void attn_combine(ushort_t* __restrict__ Op0,
                                                    const ushort_t* __restrict__ Op1,
                                                    const ushort_t* __restrict__ Op2,
                                                    const ushort_t* __restrict__ Op3,
                                                    const float* __restrict__ lsum) {
    const size_t BN = (size_t)NB * NPIX;
    size_t base = ((size_t)blockIdx.x * 256 + threadIdx.x) * 4;
    size_t bn = base >> 8;
    float li = 1.f / (lsum[bn] + lsum[BN + bn] + lsum[2*BN + bn] + lsum[3*BN + bn]);
    short4v a0 = *(short4v*)&Op0[base];
    short4v a1 = *(const short4v*)&Op1[base];
    short4v a2 = *(const short4v*)&Op2[base];
    short4v a3 = *(const short4v*)&Op3[base];
    short4v o;
    #pragma unroll
    for (int i = 0; i < 4; i++) {
        float v = (bf2f((ushort_t)a0[i]) + bf2f((ushort_t)a1[i]) +
                   bf2f((ushort_t)a2[i]) + bf2f((ushort_t)a3[i])) * li;
        o[i] = (short)f2bf(v);
    }
    *(short4v*)&Op0[base] = o;
}

// ---------------- Projection GEMM + bias + residual: out[b][c][n] f32 ----------------
__global__ __launch_bounds__(256) void proj_gemm(const ushort_t* __restrict__ aoT,
                                                 const float* __restrict__ wp, const float* __restrict__ bp,
                                                 const float* __restrict__ x, float* __restrict__ out) {
    __shared__ __align__(16) ushort_t As[64*40];
    __shared__ __align__(16) ushort_t Bs[64*40];
    int t = threadIdx.x;
    int w = t >> 6, l = t & 63, quad = l >> 4, l16 = l & 15;
    int nBase = blockIdx.x * 64, oBase = blockIdx.y * 64, b = blockIdx.z;

    const f32x4 fz = {0.f, 0.f, 0.f, 0.f};
    f32x4 acc[4];
    for (int i = 0; i < 4; i++) acc[i] = fz;

    int srow = t >> 2, sseg = t & 3;
    const float* wsrc = wp + (size_t)(oBase + srow) * CCH + sseg * 8;
    const ushort_t* bsrc = aoT + ((size_t)b * NPIX + nBase + srow) * CCH + sseg * 8;
    int sdst = srow * 40 + sseg * 8;

    for (int cb = 0; cb < 8; cb++) {
        __syncthreads();
        {
            float4 a = *(const float4*)(wsrc + cb*32);
            float4 b4 = *(const float4*)(wsrc + cb*32 + 4);
            short8 h;
            h[0]=(short)f2bf(a.x); h[1]=(short)f2bf(a.y); h[2]=(short)f2bf(a.z); h[3]=(short)f2bf(a.w);
            h[4]=(short)f2bf(b4.x); h[5]=(short)f2bf(b4.y); h[6]=(short)f2bf(b4.z); h[7]=(short)f2bf(b4.w);
            *(short8*)&As[sdst] = h;
        }
        *(short8*)&Bs[sdst] = *(const short8*)(bsrc + cb * 32);
        __syncthreads();
        short8 af = *(short8*)&As[(16*w + l16)*40 + quad*8];
        #pragma unroll
        for (int nb = 0; nb < 4; nb++) {
            short8 bf = *(short8*)&Bs[(16*nb + l16)*40 + quad*8];
            acc[nb] = __builtin_amdgcn_mfma_f32_16x16x32_bf16(af, bf, acc[nb], 0, 0, 0);
        }
    }
    #pragma unroll
    for (int nb = 0; nb < 4; nb++) {
        #pragma unroll
        for (int r = 0; r < 4; r++) {
            int orow = oBase + 16*w + quad*4 + r;
            int ncol = nBase + 16*nb + l16;
            size_t idx = ((size_t)b * CCH + orow) * NPIX + ncol;
            out[idx] = acc[nb][r] + bp[orow] + x[idx];
        }
    }
}

extern "C" void kernel_launch(void* const* d_in, const int* in_sizes, int n_in,
                              void* d_out, int out_size, void* d_ws, size_t ws_size,
                              hipStream_t stream) {
    const float* x     = (const float*)d_in[0];
    const float* gamma = (const float*)d_in[1];
    const float* beta  = (const float*)d_in[2];
    const float* wq    = (const float*)d_in[3];
    const float* bq    = (const float*)d_in[4];
    const float* wk    = (const float*)d_in[5];
    const float* bk    = (const float*)d_in[6];
    const float* wv    = (const float*)d_in[7];
    const float* bv    = (const float*)d_in[8];
    const float* wp    = (const float*)d_in[9];
    const float* bp    = (const float*)d_in[10];
    float* out = (float*)d_out;

    const size_t SZ = (size_t)NB * NPIX * CCH;     // 4.19M elems, 8 MB bf16
    float* part  = (float*)d_ws;
    float* stats = part + 512;
    float* lsum  = stats + 64;
    ushort_t* slot0 = (ushort_t*)(lsum + (size_t)NCHUNK * NB * NPIX);
    ushort_t* Op3 = slot0;
    ushort_t* qT  = slot0 + SZ;
    ushort_t* kT  = slot0 + 2*SZ;
    ushort_t* vv  = slot0 + 3*SZ;
    ushort_t* aoT = slot0 + 4*SZ;         // Op0, combined in-place -> aoT
    // d_out (16 MB) as scratch until proj_gemm:
    ushort_t* xnT = (ushort_t*)d_out;     // [0,8M): xnT, later Op1
    ushort_t* Op1 = (ushort_t*)d_out;
    ushort_t* Op2 = (ushort_t*)d_out + SZ;  // [8M,16M): wbf (pre-qkv), later Op2
    ushort_t* wbf = (ushort_t*)d_out + SZ;

    wconv<<<dim3(64, 3), 256, 0, stream>>>(wq, wk, wv, wbf);
    gn_stage1<<<256, 256, 0, stream>>>(x, part);
    gn_stage2<<<1, 64, 0, stream>>>(part, stats);
    gn_transpose<<<dim3(64, 4, 4), 256, 0, stream>>>(x, stats, gamma, beta, xnT);
    qkv_gemm<<<dim3(64, 4, 4), 256, 0, stream>>>(xnT, wbf, wbf + CCH*CCH, wbf + 2*CCH*CCH,
                                                 bq, bk, bv, qT, kT, vv);
    flash_attn<<<dim3(32, NCHUNK, 4), 256, 0, stream>>>(qT, kT, vv, aoT, Op1, Op2, Op3, lsum);
    attn_combine<<<(int)(SZ / 1024), 256, 0, stream>>>(aoT, Op1, Op2, Op3, lsum);
    proj_gemm<<<dim3(64, 4, 4), 256, 0, stream>>>(aoT, wp, bp, x, out);
}

// Round 5
// 228.434 us; speedup vs baseline: 1.5069x; 1.0910x over previous
//
#include <hip/hip_runtime.h>
#include <hip/hip_bf16.h>
#include <math.h>

// AttentionBlock: GN(8 groups) -> 1x1 conv q,k,v -> softmax(q^T k / 16) v -> 1x1 proj + residual
// b=4, c=256, hw=4096. All-bf16 MFMA pipeline.
//
// R5: flash v5 — single-barrier pipelined K-loop: global_load_lds DMA into
// double-buffered K/V (XOR-swizzled, unpadded), S^T orientation (A=K,B=Q)
// so P^T fragments are built by shuffles (no P LDS round trip), O^T accum
// with packed stores. qkv/proj rewritten as 128x128 gemm_bt with the same
// DMA pipeline. gn2 folded into gn_transpose; weight conversion folded into
// gn_stage1. 6 launches.

#define CCH 256
#define NPIX 4096
#define NB 4
#define NG 8
#define EPS 1e-5f
#define NCHUNK 4

typedef __attribute__((ext_vector_type(8))) short short8;
typedef __attribute__((ext_vector_type(4))) short short4v;
typedef __attribute__((ext_vector_type(4))) float f32x4;
typedef unsigned short ushort_t;

#define GLD16(g, l) __builtin_amdgcn_global_load_lds( \
    (const __attribute__((address_space(1))) unsigned int*)(g), \
    (__attribute__((address_space(3))) unsigned int*)(l), 16, 0, 0)

__device__ inline ushort_t f2bf(float x) {
    union { float f; unsigned u; } c; c.f = x;
    unsigned r = c.u + 0x7FFFu + ((c.u >> 16) & 1u);
    return (ushort_t)(r >> 16);
}
__device__ inline float bf2f(ushort_t h) {
    union { unsigned u; float f; } c; c.u = ((unsigned)h) << 16;
    return c.f;
}

// ---------- GN stats stage1 (blocks 0..255) + weight f32->bf16 (256..511) ----------
__global__ __launch_bounds__(256) void gn1w(const float* __restrict__ x,
                                            const float* __restrict__ wq,
                                            const float* __restrict__ wk,
                                            const float* __restrict__ wv,
                                            const float* __restrict__ wp,
                                            float* __restrict__ part,
                                            ushort_t* __restrict__ wbf,
                                            ushort_t* __restrict__ wpbf) {
    int bid = blockIdx.x;
    int t = threadIdx.x;
    if (bid >= 256) {
        int widx = bid - 256;            // 0..255
        int wi = widx >> 6;              // 0..3 : wq,wk,wv,wp
        const float* src = wi == 0 ? wq : wi == 1 ? wk : wi == 2 ? wv : wp;
        ushort_t* dst = wi == 3 ? wpbf : wbf + wi * 65536;
        int i = (widx & 63) * 1024 + t * 4;
        float4 v = *(const float4*)(src + i);
        short4v o;
        o[0] = (short)f2bf(v.x); o[1] = (short)f2bf(v.y);
        o[2] = (short)f2bf(v.z); o[3] = (short)f2bf(v.w);
        *(short4v*)(dst + i) = o;
        return;
    }
    int bg = bid >> 3;
    int slice = bid & 7;
    const float* base = x + (size_t)bg * 32 * NPIX + (size_t)slice * 16384;
    float s = 0.f, sq = 0.f;
    for (int i = t; i < 4096; i += 256) {
        float4 v = ((const float4*)base)[i];
        s  += v.x + v.y + v.z + v.w;
        sq += v.x*v.x + v.y*v.y + v.z*v.z + v.w*v.w;
    }
    for (int off = 32; off; off >>= 1) {
        s  += __shfl_down(s,  off);
        sq += __shfl_down(sq, off);
    }
    __shared__ float red[8];
    int wid = t >> 6;
    if ((t & 63) == 0) { red[wid*2] = s; red[wid*2+1] = sq; }
    __syncthreads();
    if (t == 0) {
        float ts = 0.f, tq = 0.f;
        for (int wv2 = 0; wv2 < 4; wv2++) { ts += red[wv2*2]; tq += red[wv2*2+1]; }
        part[bid*2] = ts; part[bid*2+1] = tq;
    }
}

// ---------- GN apply + transpose (stats computed inline from part) ----------
__global__ __launch_bounds__(256) void gn_transpose(const float* __restrict__ x,
                                                    const float* __restrict__ part,
                                                    const float* __restrict__ gamma,
                                                    const float* __restrict__ beta,
                                                    ushort_t* __restrict__ xnT) {
    __shared__ float T[64][68];
    __shared__ float gmean[2], grstd[2];
    int t = threadIdx.x;
    int nBase = blockIdx.x * 64;
    int cBase = blockIdx.y * 64;
    int b = blockIdx.z;
    if (t < 2) {
        int g = (cBase >> 5) + t;
        float s = 0.f, sq = 0.f;
        for (int i = 0; i < 8; i++) {
            s  += part[((b*NG + g)*8 + i)*2];
            sq += part[((b*NG + g)*8 + i)*2 + 1];
        }
        const float inv = 1.f / 131072.f;
        float mean = s * inv;
        float var = sq * inv - mean * mean;
        gmean[t] = mean;
        grstd[t] = rsqrtf(var + EPS);
    }
    __syncthreads();
    const float* xb = x + (size_t)b * CCH * NPIX;
    int n4  = (t & 15) * 4;
    int cc0 = (t >> 4) * 4;
    for (int i = 0; i < 4; i++) {
        int cc = cc0 + i;
        int c = cBase + cc;
        int gi = cc >> 5;
        float ga = gamma[c] * grstd[gi];
        float be = beta[c] - gmean[gi] * ga;
        float4 v = *(const float4*)&xb[(size_t)c * NPIX + nBase + n4];
        T[cc][n4+0] = v.x * ga + be;
        T[cc][n4+1] = v.y * ga + be;
        T[cc][n4+2] = v.z * ga + be;
        T[cc][n4+3] = v.w * ga + be;
    }
    __syncthreads();
    int nn  = t >> 2;
    int ci0 = (t & 3) * 16;
    short8 o0, o1;
    for (int j = 0; j < 8; j++) {
        o0[j] = (short)f2bf(T[ci0 + j][nn]);
        o1[j] = (short)f2bf(T[ci0 + 8 + j][nn]);
    }
    ushort_t* dst = xnT + ((size_t)b * NPIX + nBase + nn) * CCH + cBase + ci0;
    *(short8*)dst = o0;
    *((short8*)dst + 1) = o1;
}

// ---------- QKV: three 128x128-tile GEMMs in one grid (z = q,k,v) ----------
// A[M][256] x B[N][256] -> C[m][n] (D = A·B^T). DMA-pipelined, dbuf LDS,
// one barrier per K-step. z<2: M=16384(pix) N=256(c), C=q/kT[n'][c], bias[n].
// z==2: M=256(c) N=16384(pix), C=vv[b][c][n], bias[m].
__global__ __launch_bounds__(256, 2) void qkv3(const ushort_t* __restrict__ xnT,
                                               const ushort_t* __restrict__ wbf,
                                               const float* __restrict__ bq,
                                               const float* __restrict__ bk,
                                               const float* __restrict__ bv,
                                               ushort_t* __restrict__ qT,
                                               ushort_t* __restrict__ kT,
                                               ushort_t* __restrict__ vv) {
    __shared__ __align__(16) ushort_t As[2][4096];
    __shared__ __align__(16) ushort_t Bs[2][4096];
    int t = threadIdx.x;
    int w = t >> 6, l = t & 63, quad = l >> 4, l16 = l & 15;
    int z = blockIdx.z;
    const ushort_t* A; const ushort_t* B; int mBase, nBase;
    if (z < 2) { A = xnT; B = wbf + z * 65536; mBase = blockIdx.x * 128; nBase = blockIdx.y * 128; }
    else       { A = wbf + 131072; B = xnT;    mBase = blockIdx.y * 128; nBase = blockIdx.x * 128; }
    int m0 = (w & 1) * 64, n0 = (w >> 1) * 64;

    const f32x4 fz = {0.f, 0.f, 0.f, 0.f};
    f32x4 acc[4][4];
    #pragma unroll
    for (int i = 0; i < 4; i++)
        #pragma unroll
        for (int j = 0; j < 4; j++) acc[i][j] = fz;

    int srow = t >> 2;
    int slc  = (t & 3) ^ ((t >> 2) & 3);
    int sldso = (t >> 6) * 512;

    // prefetch k-block 0
    #pragma unroll
    for (int j = 0; j < 2; j++) {
        int row = 64*j + srow;
        GLD16(A + (size_t)(mBase + row) * 256 + slc * 8, &As[0][j*2048 + sldso]);
        GLD16(B + (size_t)(nBase + row) * 256 + slc * 8, &Bs[0][j*2048 + sldso]);
    }
    int buf = 0;
    for (int kb = 0; kb < 8; kb++) {
        __syncthreads();   // drains DMA for buf, and prior reads of buf^1
        if (kb < 7) {
            #pragma unroll
            for (int j = 0; j < 2; j++) {
                int row = 64*j + srow;
                GLD16(A + (size_t)(mBase + row) * 256 + (kb+1)*32 + slc * 8, &As[buf^1][j*2048 + sldso]);
                GLD16(B + (size_t)(nBase + row) * 256 + (kb+1)*32 + slc * 8, &Bs[buf^1][j*2048 + sldso]);
            }
        }
        short8 af[4], bfr[4];
        #pragma unroll
        for (int mb = 0; mb < 4; mb++)
            af[mb] = *(short8*)&As[buf][(m0 + mb*16 + l16)*32 + ((quad ^ (l16 & 3)) * 8)];
        #pragma unroll
        for (int nb = 0; nb < 4; nb++)
            bfr[nb] = *(short8*)&Bs[buf][(n0 + nb*16 + l16)*32 + ((quad ^ (l16 & 3)) * 8)];
        #pragma unroll
        for (int mb = 0; mb < 4; mb++)
            #pragma unroll
            for (int nb = 0; nb < 4; nb++)
                acc[mb][nb] = __builtin_amdgcn_mfma_f32_16x16x32_bf16(af[mb], bfr[nb], acc[mb][nb], 0, 0, 0);
        buf ^= 1;
    }
    // epilogue
    if (z < 2) {
        const float* bias = z ? bk : bq;
        ushort_t* C = z ? kT : qT;
        #pragma unroll
        for (int nb = 0; nb < 4; nb++) {
            int n = nBase + n0 + nb*16 + l16;
            float bb = bias[n];
            #pragma unroll
            for (int mb = 0; mb < 4; mb++)
                #pragma unroll
                for (int r = 0; r < 4; r++) {
                    int m = mBase + m0 + mb*16 + quad*4 + r;
                    C[(size_t)m * 256 + n] = f2bf(acc[mb][nb][r] + bb);
                }
        }
    } else {
        #pragma unroll
        for (int mb = 0; mb < 4; mb++)
            #pragma unroll
            for (int r = 0; r < 4; r++) {
                int m = mBase + m0 + mb*16 + quad*4 + r;
                float bb = bv[m];
                #pragma unroll
                for (int nb = 0; nb < 4; nb++) {
                    int n = nBase + n0 + nb*16 + l16;
                    vv[((size_t)(n >> 12) * 256 + m) * 4096 + (n & 4095)] = f2bf(acc[mb][nb][r] + bb);
                }
            }
    }
}

// ---------- Flash attention v5 ----------
// Grid (32 qtiles(128q), NCHUNK, 4 b), block 256 = 4 waves; wave: 32q as two
// 16-row subtiles. S^T = mfma(A=K, B=Q); P^T B-frags built via shuffles;
// O^T accumulated; K/V double-buffered in LDS via global_load_lds DMA
// (XOR-swizzled unpadded layout), ONE barrier per kv-tile.
__global__ __launch_bounds__(256, 2) void flash_attn(const ushort_t* __restrict__ qT,
                                                     const ushort_t* __restrict__ kT,
                                                     const ushort_t* __restrict__ vv,
                                                     ushort_t* __restrict__ Op0,
                                                     ushort_t* __restrict__ Op1,
                                                     ushort_t* __restrict__ Op2,
                                                     ushort_t* __restrict__ Op3,
                                                     float* __restrict__ lsum) {
    __shared__ __align__(16) ushort_t Ks[2][8192];   // [kv 32][k 256] unpadded, chunk^=(row&7)
    __shared__ __align__(16) ushort_t Vs[2][8192];   // [c 256][m 32] unpadded, chunk^=(c&3)
    int t = threadIdx.x;
    int w = t >> 6, l = t & 63, quad = l >> 4, l16 = l & 15;
    int qBase = blockIdx.x * 128, chunk = blockIdx.y, b = blockIdx.z;
    int qw = qBase + w * 32;

    // Q fragments (B-layout [n=l16][k=quad*8+j]) for both subtiles
    short8 qf[2][8];
    #pragma unroll
    for (int s = 0; s < 2; s++) {
        const ushort_t* qrow = qT + ((size_t)b * NPIX + qw + s*16 + l16) * CCH + quad * 8;
        #pragma unroll
        for (int cb = 0; cb < 8; cb++) qf[s][cb] = *(const short8*)(qrow + cb * 32);
    }

    const f32x4 fz = {0.f, 0.f, 0.f, 0.f};
    f32x4 accO[2][16];          // O^T: [sub][c-block], lane = (c_local=quad*4+r, q=l16)
    #pragma unroll
    for (int s = 0; s < 2; s++)
        #pragma unroll
        for (int i = 0; i < 16; i++) accO[s][i] = fz;
    float lq[2] = {0.f, 0.f};

    // DMA staging maps (lane-linear LDS: elem = j*2048 + t*8)
    int kr  = t >> 5;                       // K: row-within-8 = t>>5, chunk = t&31
    int klc = (t & 31) ^ kr;                //   logical chunk (xor row&7)
    int vc  = t >> 2;                       // V: row-within-64 = t>>2, chunk = t&3
    int vlc = (t & 3) ^ (vc & 3);
    int sldso = (t >> 6) * 512;
    const ushort_t* kbase = kT + (size_t)b * NPIX * CCH;
    const ushort_t* vbase = vv + (size_t)b * CCH * NPIX;

    const float SC = 0.0625f * 1.44269504089f;
    int mStart = chunk * (NPIX / NCHUNK);
    int mEnd = mStart + NPIX / NCHUNK;

    // prefetch tile 0 into buf 0
    #pragma unroll
    for (int j = 0; j < 4; j++) {
        GLD16(kbase + (size_t)(mStart + 8*j + kr) * CCH + klc * 8, &Ks[0][j*2048 + sldso]);
        GLD16(vbase + (size_t)(64*j + vc) * NPIX + mStart + vlc * 8, &Vs[0][j*2048 + sldso]);
    }
    int buf = 0;
    for (int mBase = mStart; mBase < mEnd; mBase += 32) {
        __syncthreads();   // drains this wave's DMA (vmcnt 0) + all waves done reading buf^1
        if (mBase + 32 < mEnd) {
            #pragma unroll
            for (int j = 0; j < 4; j++) {
                GLD16(kbase + (size_t)(mBase + 32 + 8*j + kr) * CCH + klc * 8, &Ks[buf^1][j*2048 + sldso]);
                GLD16(vbase + (size_t)(64*j + vc) * NPIX + mBase + 32 + vlc * 8, &Vs[buf^1][j*2048 + sldso]);
            }
        }
        // S^T = K · Q^T : D[kv_local][q]
        f32x4 sT[2][2];    // [sub][kv-half]
        sT[0][0] = fz; sT[0][1] = fz; sT[1][0] = fz; sT[1][1] = fz;
        #pragma unroll
        for (int cb = 0; cb < 8; cb++) {
            int ksw = ((cb*4 + quad) ^ (l16 & 7)) * 8;
            short8 k0 = *(short8*)&Ks[buf][l16 * 256 + ksw];
            short8 k1 = *(short8*)&Ks[buf][(16 + l16) * 256 + ksw];
            sT[0][0] = __builtin_amdgcn_mfma_f32_16x16x32_bf16(k0, qf[0][cb], sT[0][0], 0, 0, 0);
            sT[1][0] = __builtin_amdgcn_mfma_f32_16x16x32_bf16(k0, qf[1][cb], sT[1][0], 0, 0, 0);
            sT[0][1] = __builtin_amdgcn_mfma_f32_16x16x32_bf16(k1, qf[0][cb], sT[0][1], 0, 0, 0);
            sT[1][1] = __builtin_amdgcn_mfma_f32_16x16x32_bf16(k1, qf[1][cb], sT[1][1], 0, 0, 0);
        }
        // exp + P^T fragment assembly (shuffle transpose, no LDS)
        short8 pf[2];
        int srcA = ((quad & 1) * 2) * 16 + l16;
        #pragma unroll
        for (int s = 0; s < 2; s++) {
            float ph[2][4];
            #pragma unroll
            for (int h = 0; h < 2; h++)
                #pragma unroll
                for (int r = 0; r < 4; r++) {
                    ph[h][r] = exp2f(sT[s][h][r] * SC);
                    lq[s] += ph[h][r];
                }
            bool hi2 = quad >= 2;
            #pragma unroll
            for (int jj = 0; jj < 4; jj++) {
                float a0 = __shfl(ph[0][jj], srcA);
                float a1 = __shfl(ph[1][jj], srcA);
                float b0 = __shfl(ph[0][jj], srcA + 16);
                float b1 = __shfl(ph[1][jj], srcA + 16);
                pf[s][jj]     = (short)f2bf(hi2 ? a1 : a0);
                pf[s][4 + jj] = (short)f2bf(hi2 ? b1 : b0);
            }
        }
        // O^T += V · P : D[c_local][q]
        #pragma unroll
        for (int cblk = 0; cblk < 16; cblk++) {
            short8 vf = *(short8*)&Vs[buf][(cblk*16 + l16)*32 + ((quad ^ (l16 & 3)) * 8)];
            accO[0][cblk] = __builtin_amdgcn_mfma_f32_16x16x32_bf16(vf, pf[0], accO[0][cblk], 0, 0, 0);
            accO[1][cblk] = __builtin_amdgcn_mfma_f32_16x16x32_bf16(vf, pf[1], accO[1][cblk], 0, 0, 0);
        }
        buf ^= 1;
    }

    // row-sums: reduce across the 4 quads (lanes l16, l16+16, +32, +48)
    #pragma unroll
    for (int s = 0; s < 2; s++) {
        float v = lq[s];
        v += __shfl_xor(v, 16);
        v += __shfl_xor(v, 32);
        if (quad == 0)
            lsum[((size_t)chunk * NB + b) * NPIX + qw + s*16 + l16] = v;
    }
    // unnormalized partial O (bf16), packed 4-wide along c
    ushort_t* op = chunk == 0 ? Op0 : chunk == 1 ? Op1 : chunk == 2 ? Op2 : Op3;
    #pragma unroll
    for (int s = 0; s < 2; s++) {
        size_t rowb = ((size_t)b * NPIX + qw + s*16 + l16) * CCH;
        #pragma unroll
        for (int cblk = 0; cblk < 16; cblk++) {
            short4v o;
            #pragma unroll
            for (int r = 0; r < 4; r++) o[r] = (short)f2bf(accO[s][cblk][r]);
            *(short4v*)&op[rowb + cblk*16 + quad*4] = o;
        }
    }
}

// ---------- Combine: aoT = (Op0+Op1+Op2+Op3)/(l0+l1+l2+l3), in-place Op0 ----------
__global__ __launch_bounds__(256) void attn_combine(ushort_t* __restrict__ Op0,
                                                    const ushort_t* __restrict__ Op1,
                                                    const ushort_t* __restrict__ Op2,
                                                    const ushort_t* __restrict__ Op3,
                                                    const float* __restrict__ lsum) {
    const size_t BN = (size_t)NB * NPIX;
    size_t base = ((size_t)blockIdx.x * 256 + threadIdx.x) * 4;
    size_t bn = base >> 8;
    float li = 1.f / (lsum[bn] + lsum[BN + bn] + lsum[2*BN + bn] + lsum[3*BN + bn]);
    short4v a0 = *(short4v*)&Op0[base];
    short4v a1 = *(const short4v*)&Op1[base];
    short4v a2 = *(const short4v*)&Op2[base];
    short4v a3 = *(const short4v*)&Op3[base];
    short4v o;
    #pragma unroll
    for (int i = 0; i < 4; i++) {
        float v = (bf2f((ushort_t)a0[i]) + bf2f((ushort_t)a1[i]) +
                   bf2f((ushort_t)a2[i]) + bf2f((ushort_t)a3[i])) * li;
        o[i] = (short)f2bf(v);
    }
    *(short4v*)&Op0[base] = o;
}

// ---------- Projection GEMM + bias + residual (f32 out) ----------
__global__ __launch_bounds__(256, 2) void projk(const ushort_t* __restrict__ wpbf,
                                                const ushort_t* __restrict__ aoT,
                                                const float* __restrict__ bp,
                                                const float* __restrict__ x,
                                                float* __restrict__ out) {
    __shared__ __align__(16) ushort_t As[2][4096];
    __shared__ __align__(16) ushort_t Bs[2][4096];
    int t = threadIdx.x;
    int w = t >> 6, l = t & 63, quad = l >> 4, l16 = l & 15;
    int mBase = blockIdx.y * 128, nBase = blockIdx.x * 128;
    int m0 = (w & 1) * 64, n0 = (w >> 1) * 64;

    const f32x4 fz = {0.f, 0.f, 0.f, 0.f};
    f32x4 acc[4][4];
    #pragma unroll
    for (int i = 0; i < 4; i++)
        #pragma unroll
        for (int j = 0; j < 4; j++) acc[i][j] = fz;

    int srow = t >> 2;
    int slc  = (t & 3) ^ ((t >> 2) & 3);
    int sldso = (t >> 6) * 512;

    #pragma unroll
    for (int j = 0; j < 2; j++) {
        int row = 64*j + srow;
        GLD16(wpbf + (size_t)(mBase + row) * 256 + slc * 8, &As[0][j*2048 + sldso]);
        GLD16(aoT  + (size_t)(nBase + row) * 256 + slc * 8, &Bs[0][j*2048 + sldso]);
    }
    int buf = 0;
    for (int kb = 0; kb < 8; kb++) {
        __syncthreads();
        if (kb < 7) {
            #pragma unroll
            for (int j = 0; j < 2; j++) {
                int row = 64*j + srow;
                GLD16(wpbf + (size_t)(mBase + row) * 256 + (kb+1)*32 + slc * 8, &As[buf^1][j*2048 + sldso]);
                GLD16(aoT  + (size_t)(nBase + row) * 256 + (kb+1)*32 + slc * 8, &Bs[buf^1][j*2048 + sldso]);
            }
        }
        short8 af[4], bfr[4];
        #pragma unroll
        for (int mb = 0; mb < 4; mb++)
            af[mb] = *(short8*)&As[buf][(m0 + mb*16 + l16)*32 + ((quad ^ (l16 & 3)) * 8)];
        #pragma unroll
        for (int nb = 0; nb < 4; nb++)
            bfr[nb] = *(short8*)&Bs[buf][(n0 + nb*16 + l16)*32 + ((quad ^ (l16 & 3)) * 8)];
        #pragma unroll
        for (int mb = 0; mb < 4; mb++)
            #pragma unroll
            for (int nb = 0; nb < 4; nb++)
                acc[mb][nb] = __builtin_amdgcn_mfma_f32_16x16x32_bf16(af[mb], bfr[nb], acc[mb][nb], 0, 0, 0);
        buf ^= 1;
    }
    #pragma unroll
    for (int mb = 0; mb < 4; mb++)
        #pragma unroll
        for (int r = 0; r < 4; r++) {
            int m = mBase + m0 + mb*16 + quad*4 + r;
            float bb = bp[m];
            #pragma unroll
            for (int nb = 0; nb < 4; nb++) {
                int n = nBase + n0 + nb*16 + l16;
                size_t idx = ((size_t)(n >> 12) * 256 + m) * 4096 + (n & 4095);
                out[idx] = acc[mb][nb][r] + bb + x[idx];
            }
        }
}

extern "C" void kernel_launch(void* const* d_in, const int* in_sizes, int n_in,
                              void* d_out, int out_size, void* d_ws, size_t ws_size,
                              hipStream_t stream) {
    const float* x     = (const float*)d_in[0];
    const float* gamma = (const float*)d_in[1];
    const float* beta  = (const float*)d_in[2];
    const float* wq    = (const float*)d_in[3];
    const float* bq    = (const float*)d_in[4];
    const float* wk    = (const float*)d_in[5];
    const float* bk    = (const float*)d_in[6];
    const float* wv    = (const float*)d_in[7];
    const float* bv    = (const float*)d_in[8];
    const float* wp    = (const float*)d_in[9];
    const float* bp    = (const float*)d_in[10];
    float* out = (float*)d_out;

    const size_t SZ = (size_t)NB * NPIX * CCH;     // 4.19M elems, 8 MB bf16
    // ws: part[512]f32, lsum[4*16384]f32, wpbf[65536]bf16, 5 bf16 slots (~40.4MB)
    float* part  = (float*)d_ws;
    float* lsum  = part + 512;
    ushort_t* wpbf = (ushort_t*)(lsum + (size_t)NCHUNK * NB * NPIX);
    ushort_t* slot0 = wpbf + 65536;
    ushort_t* Op3 = slot0;
    ushort_t* qT  = slot0 + SZ;
    ushort_t* kT  = slot0 + 2*SZ;
    ushort_t* vvp = slot0 + 3*SZ;
    ushort_t* aoT = slot0 + 4*SZ;          // Op0, combined in-place -> aoT
    // d_out (16 MB) as scratch until projk:
    ushort_t* xnT = (ushort_t*)d_out;      // [0,8M): xnT, later Op1
    ushort_t* Op1 = (ushort_t*)d_out;
    ushort_t* Op2 = (ushort_t*)d_out + SZ; // [8M,16M): wbf (pre-qkv), later Op2
    ushort_t* wbf = (ushort_t*)d_out + SZ; // wq,wk,wv bf16

    gn1w<<<512, 256, 0, stream>>>(x, wq, wk, wv, wp, part, wbf, wpbf);
    gn_transpose<<<dim3(64, 4, 4), 256, 0, stream>>>(x, part, gamma, beta, xnT);
    qkv3<<<dim3(128, 2, 3), 256, 0, stream>>>(xnT, wbf, bq, bk, bv, qT, kT, vvp);
    flash_attn<<<dim3(32, NCHUNK, 4), 256, 0, stream>>>(qT, kT, vvp, aoT, Op1, Op2, Op3, lsum);
    attn_combine<<<(int)(SZ / 1024), 256, 0, stream>>>(aoT, Op1, Op2, Op3, lsum);
    projk<<<dim3(128, 2), 256, 0, stream>>>(wpbf, aoT, bp, x, out);
}